// Round 4
// baseline (462.396 us; speedup 1.0000x reference)
//
#include <hip/hip_runtime.h>
#include <math.h>

typedef __attribute__((ext_vector_type(8))) short bf16x8;
typedef __attribute__((ext_vector_type(4))) float f32x4;
typedef __attribute__((ext_vector_type(4))) unsigned short us4;
typedef __attribute__((ext_vector_type(8))) unsigned short us8;

static constexpr int kN  = 50000;
static constexpr int kE  = 800000;
static constexpr int kNBUK = 98;     // ceil(50000/512), bucket = dst>>9
static constexpr int kCAP  = 9216;   // per-bucket payload cap (mean 8163 + 11.6 sigma)

__device__ __forceinline__ float b2f(unsigned short u) {
  union { unsigned u; float f; } x; x.u = ((unsigned)u) << 16; return x.f;
}
__device__ __forceinline__ unsigned short f2b(float f) {
  union { float f; unsigned u; } x; x.f = f;
  unsigned u = x.u;
  unsigned r = (u + 0x7fffu + ((u >> 16) & 1u)) >> 16;
  return (unsigned short)r;
}

// ---------------- fused prep: Wt_a, Wt_b (bf16 [256][256]), W1T (bf16 [128][256])
__global__ __launch_bounds__(256)
void k_prep(const float* __restrict__ Wa, const float* __restrict__ Wb,
            const float* __restrict__ W1,
            unsigned short* __restrict__ wta, unsigned short* __restrict__ wtb,
            unsigned short* __restrict__ w1t) {
  int b = blockIdx.x, t = threadIdx.x;
  if (b < 256) {
    int i = b * 256 + t, j = i >> 8, k = i & 255;
    wta[j * 256 + k] = f2b(Wa[k * 256 + j]);
  } else if (b < 512) {
    int i = (b - 256) * 256 + t, j = i >> 8, k = i & 255;
    wtb[j * 256 + k] = f2b(Wb[k * 256 + j]);
  } else {
    int i = (b - 512) * 256 + t, j = i >> 8, k = i & 255;  // j<128
    w1t[j * 256 + k] = f2b(W1[k * 128 + j]);
  }
}

// ---------------- feat = h @ W + fused el/er, LDS tile GEMM ----------------
__global__ __launch_bounds__(512, 4)
void k_gemm(const float* __restrict__ h,
            const unsigned short* __restrict__ wta,
            const unsigned short* __restrict__ wtb,
            const float* __restrict__ ala, const float* __restrict__ ara,
            const float* __restrict__ alb, const float* __restrict__ arb,
            unsigned short* __restrict__ fa, unsigned short* __restrict__ fb,
            float* __restrict__ ela, float* __restrict__ era,
            float* __restrict__ elb, float* __restrict__ erb) {
  __shared__ us8 la[128 * 8];                  // 16KB
  __shared__ us8 lb[256 * 8];                  // 32KB
  const int z = blockIdx.y;
  const unsigned short* wt = z ? wtb : wta;
  unsigned short* f = z ? fb : fa;
  const float* al = z ? alb : ala;
  const float* ar = z ? arb : ara;
  float* el = z ? elb : ela;
  float* er = z ? erb : era;
  const int m0 = blockIdx.x * 128;
  const int t = threadIdx.x;
  const int lane = t & 63;
  const int wave = t >> 6;                     // 0..7
  const int col = lane & 15;
  const int quad = lane >> 4;
  const int mw = (wave >> 2) * 64;             // 0 or 64
  const int nw = (wave & 3) * 64;              // 0,64,128,192
  f32x4 acc[4][4];
#pragma unroll
  for (int i = 0; i < 4; ++i)
#pragma unroll
    for (int j = 0; j < 4; ++j) acc[i][j] = (f32x4){0.f, 0.f, 0.f, 0.f};

  for (int ks = 0; ks < 4; ++ks) {
    const int k0 = ks * 64;
    __syncthreads();
    // stage A: 128 rows x 64 k, fp32 -> bf16. 2048 8B-units, 4 iters.
#pragma unroll
    for (int i = 0; i < 4; ++i) {
      int idx = i * 512 + t;
      int r = idx >> 4, g = (idx >> 1) & 7, half = idx & 1;
      int gr = m0 + r;
      f32x4 v = {0.f, 0.f, 0.f, 0.f};
      if (gr < kN) v = *(const f32x4*)(h + (size_t)gr * 256 + k0 + g * 8 + half * 4);
      us4 o;
      o.x = f2b(v.x); o.y = f2b(v.y); o.z = f2b(v.z); o.w = f2b(v.w);
      *(us4*)((unsigned short*)&la[r * 8 + (g ^ (r & 7))] + half * 4) = o;
    }
    // stage B: 256 rows x 64 k bf16. 2048 16B-units, 4 iters.
#pragma unroll
    for (int i = 0; i < 4; ++i) {
      int idx = i * 512 + t;
      int r = idx >> 3, g = idx & 7;
      lb[r * 8 + (g ^ (r & 7))] = *(const us8*)(wt + r * 256 + k0 + g * 8);
    }
    __syncthreads();
#pragma unroll
    for (int k32 = 0; k32 < 64; k32 += 32) {
      const int cg = (k32 >> 3) + quad;
      bf16x8 af[4], bf[4];
#pragma unroll
      for (int s = 0; s < 4; ++s) {
        int arow = mw + s * 16 + col;
        af[s] = (bf16x8)la[arow * 8 + (cg ^ (arow & 7))];
        int brow = nw + s * 16 + col;
        bf[s] = (bf16x8)lb[brow * 8 + (cg ^ (brow & 7))];
      }
#pragma unroll
      for (int i = 0; i < 4; ++i)
#pragma unroll
        for (int j = 0; j < 4; ++j)
          acc[i][j] = __builtin_amdgcn_mfma_f32_16x16x32_bf16(af[i], bf[j],
                                                              acc[i][j], 0, 0, 0);
    }
  }
  // epilogue 1: feat store (C row = quad*4+reg, col = lane&15)
#pragma unroll
  for (int i = 0; i < 4; ++i) {
#pragma unroll
    for (int r = 0; r < 4; ++r) {
      int row = m0 + mw + i * 16 + quad * 4 + r;
      if (row < kN) {
#pragma unroll
        for (int j = 0; j < 4; ++j)
          f[(size_t)row * 256 + nw + j * 16 + col] = f2b(acc[i][j][r]);
      }
    }
  }
  // epilogue 2: el/er for this wave's 2 heads (hA = cols nw..nw+31, hB next)
  float alv[4], arv[4];
#pragma unroll
  for (int j = 0; j < 4; ++j) {
    alv[j] = al[nw + j * 16 + col];
    arv[j] = ar[nw + j * 16 + col];
  }
  const int hA = nw >> 5;
#pragma unroll
  for (int i = 0; i < 4; ++i) {
#pragma unroll
    for (int r = 0; r < 4; ++r) {
      float pAl = acc[i][0][r] * alv[0] + acc[i][1][r] * alv[1];
      float pBl = acc[i][2][r] * alv[2] + acc[i][3][r] * alv[3];
      float pAr = acc[i][0][r] * arv[0] + acc[i][1][r] * arv[1];
      float pBr = acc[i][2][r] * arv[2] + acc[i][3][r] * arv[3];
#pragma unroll
      for (int off = 1; off < 16; off <<= 1) {
        pAl += __shfl_xor(pAl, off);
        pBl += __shfl_xor(pBl, off);
        pAr += __shfl_xor(pAr, off);
        pBr += __shfl_xor(pBr, off);
      }
      int row = m0 + mw + i * 16 + quad * 4 + r;
      if (col == 0 && row < kN) {
        el[row * 8 + hA] = pAl;
        el[row * 8 + hA + 1] = pBl;
        er[row * 8 + hA] = pAr;
        er[row * 8 + hA + 1] = pBr;
      }
    }
  }
}

// ---------------- CSR build via radix partition ----------------------------
__global__ __launch_bounds__(256)
void k_part(const int* __restrict__ sa, const int* __restrict__ da,
            const int* __restrict__ sb, const int* __restrict__ db,
            int* __restrict__ cnt, unsigned* __restrict__ pay) {
  int y = blockIdx.y;
  const int* s = y ? sb : sa;
  const int* d = y ? db : da;
  unsigned* p = pay + (size_t)y * kNBUK * kCAP;
  int* cn = cnt + y * kNBUK;
  __shared__ unsigned stash[6400];              // 25.6KB
  __shared__ int h[kNBUK];
  int t = threadIdx.x;
  if (t < kNBUK) h[t] = 0;
  __syncthreads();
  int e0 = blockIdx.x * 6400;
#pragma unroll 5
  for (int it = 0; it < 25; ++it) {
    int e = e0 + it * 256 + t;
    int sv = s[e], dv = d[e];
    int b = dv >> 9;
    stash[it * 256 + t] = (unsigned)sv | ((unsigned)(dv & 511) << 16) |
                          ((unsigned)b << 25);
    atomicAdd(&h[b], 1);
  }
  __syncthreads();
  if (t < kNBUK) h[t] = atomicAdd(&cn[t], h[t]);  // h becomes block's cursor
  __syncthreads();
#pragma unroll 5
  for (int it = 0; it < 25; ++it) {
    unsigned w = stash[it * 256 + t];
    int b = w >> 25;
    int slot = atomicAdd(&h[b], 1);
    p[b * kCAP + slot] = w & 0x1FFFFFFu;
  }
}

// k_bscan: exclusive scan of 2x98 bucket counts -> global es/rp bases.
__global__ __launch_bounds__(256)
void k_bscan(const int* __restrict__ cnt, int* __restrict__ bbase,
             int* __restrict__ rpa, int* __restrict__ rpb) {
  __shared__ int buf[2][128];
  int t = threadIdx.x;
  int y = t >> 7, i = t & 127;
  int x = (i < kNBUK) ? cnt[y * kNBUK + i] : 0;
  buf[y][i] = x;
  __syncthreads();
  for (int off = 1; off < 128; off <<= 1) {
    int v = (i >= off) ? buf[y][i - off] : 0;
    __syncthreads();
    buf[y][i] += v;
    __syncthreads();
  }
  if (i < kNBUK) bbase[y * kNBUK + i] = buf[y][i] - x;
  if (t == 0) { rpa[kN] = kE; rpb[kN] = kE; }
}

// k_bucket: one block per (bucket, graph). LDS histogram + pair scan ->
// writes rp segment AND scatters es via LDS cursor atomics.
__global__ __launch_bounds__(256)
void k_bucket(const int* __restrict__ cnt, const int* __restrict__ bbase,
              const unsigned* __restrict__ pay,
              int* __restrict__ rpa, int* __restrict__ rpb,
              int* __restrict__ esa, int* __restrict__ esb) {
  int b = blockIdx.x, y = blockIdx.y;
  int* rp = y ? rpb : rpa;
  int* es = y ? esb : esa;
  const unsigned* p = pay + ((size_t)y * kNBUK + b) * kCAP;
  int c = cnt[y * kNBUK + b];
  int base = bbase[y * kNBUK + b];
  __shared__ unsigned pl[kCAP];                 // 36.9KB
  __shared__ int h[512];
  __shared__ int buf[256];
  int t = threadIdx.x;
  h[t] = 0; h[t + 256] = 0;
  __syncthreads();
  for (int i = t; i < c; i += 256) {
    unsigned w = p[i];
    pl[i] = w;
    atomicAdd(&h[(w >> 16) & 511], 1);
  }
  __syncthreads();
  int a = h[2 * t], b1 = h[2 * t + 1];
  int s2 = a + b1;
  buf[t] = s2;
  __syncthreads();
  for (int off = 1; off < 256; off <<= 1) {
    int v = (t >= off) ? buf[t - off] : 0;
    __syncthreads();
    buf[t] += v;
    __syncthreads();
  }
  int ex = buf[t] - s2;                         // exclusive pair base
  int g0 = b * 512 + 2 * t;
  if (g0 < kN) rp[g0] = base + ex;
  if (g0 + 1 < kN) rp[g0 + 1] = base + ex + a;
  h[2 * t] = ex;                                // h becomes local cursors
  h[2 * t + 1] = ex + a;
  __syncthreads();
  for (int i = t; i < c; i += 256) {
    unsigned w = pl[i];
    int slot = atomicAdd(&h[(w >> 16) & 511], 1);
    es[base + slot] = (int)(w & 0xFFFFu);
  }
}

// ---------------- GAT aggregate: one wave per TWO adjacent dst nodes -------
// Theory: single-node waves alternate a serial phase1 chain (es->el->exp,
// zero gather bytes outstanding) with short phase2 bursts -> memory pipe
// starves (dur pinned at 128us while VALUBusy moved). Two nodes per wave
// interleave independent chains and double the gather burst depth.
// phase1: lanes = (edge-octet, head) = 8x8, both nodes back-to-back.
// phase2: pair-ops (2 edges, 16B/lane us8) interleaved A/B, 4 loads in
// flight. Epilogue: halves-combine + denom shfl, rcp, fast ELU; stores for
// the 2 adjacent nodes are contiguous (2KB per wave).
__global__ __launch_bounds__(256)
void k_agg(const int* __restrict__ rpa, const int* __restrict__ rpb,
           const int* __restrict__ esa, const int* __restrict__ esb,
           const float* __restrict__ ela, const float* __restrict__ era,
           const float* __restrict__ elb, const float* __restrict__ erb,
           const unsigned short* __restrict__ fa,
           const unsigned short* __restrict__ fb,
           const float* __restrict__ biasa, const float* __restrict__ biasb,
           float* __restrict__ za, unsigned short* __restrict__ zb) {
  __shared__ float wls[4][2][256];             // 32 edges x 8 heads x 2 nodes
  __shared__ int sls[4][2][32];
  int bx = blockIdx.x;
  int y = bx >= 6250;
  int nb = y ? bx - 6250 : bx;
  const int* rp = y ? rpb : rpa;
  const int* es = y ? esb : esa;
  const float* el = y ? elb : ela;
  const float* er = y ? erb : era;
  const unsigned short* feat = y ? fb : fa;
  const float* bias = y ? biasb : biasa;
  int lane = threadIdx.x & 63;
  int wave = threadIdx.x >> 6;
  int nA = nb * 8 + wave * 2;                  // two adjacent nodes per wave
  int nB = nA + 1;
  int hh = lane >> 3;                          // phase1 edge-slot
  int h = lane & 7;                            // phase1 head
  int half = lane >> 5;                        // phase2: which edge of pair
  int l5 = lane & 31;
  int h2 = l5 >> 2;                            // phase2 head (dims l5*8..+7)
  unsigned idx16 = (unsigned)l5 * 16u;         // byte offset in feat row
  float erhA = er[nA * 8 + h];
  float erhB = er[nB * 8 + h];
  int e0A = rp[nA], e1A = rp[nA + 1], e1B = rp[nB + 1];
  int cbA = e0A, cbB = e1A;                    // nB starts where nA ends
  float dsumA = 0.f, dsumB = 0.f;
  float aA0 = 0.f, aA1 = 0.f, aA2 = 0.f, aA3 = 0.f;
  float aA4 = 0.f, aA5 = 0.f, aA6 = 0.f, aA7 = 0.f;
  float aB0 = 0.f, aB1 = 0.f, aB2 = 0.f, aB3 = 0.f;
  float aB4 = 0.f, aB5 = 0.f, aB6 = 0.f, aB7 = 0.f;

  while (cbA < e1A || cbB < e1B) {
    int cntA = e1A - cbA; cntA = cntA < 0 ? 0 : (cntA > 32 ? 32 : cntA);
    int cntB = e1B - cbB; cntB = cntB < 0 ? 0 : (cntB > 32 ? 32 : cntB);
    // phase 1: both nodes' (es -> el -> exp) chains interleaved
#pragma unroll
    for (int it = 0; it < 4; ++it) {
      int j = it * 8 + hh;
      bool vA = j < cntA, vB = j < cntB;
      int sA = vA ? es[cbA + j] : 0;
      int sB = vB ? es[cbB + j] : 0;
      float xA = vA ? *(const float*)((const char*)el + ((unsigned)sA << 5) +
                                      ((unsigned)h << 2)) : 0.f;
      float xB = vB ? *(const float*)((const char*)el + ((unsigned)sB << 5) +
                                      ((unsigned)h << 2)) : 0.f;
      float eA = xA + erhA, eB = xB + erhB;
      eA = fmaxf(eA, 0.2f * eA);               // LeakyReLU(0.2)
      eB = fmaxf(eB, 0.2f * eB);
      float wA = __expf(eA), wB = __expf(eB);
      wls[wave][0][it * 64 + lane] = wA;       // slot j*8+h
      wls[wave][1][it * 64 + lane] = wB;
      if (vA) dsumA += wA;
      if (vB) dsumB += wB;
      if (h == 0) {
        if (vA) sls[wave][0][j] = sA;
        if (vB) sls[wave][1][j] = sB;
      }
    }
    // phase 2: interleaved pair-ops, 4 x 512B gathers in flight
    int jmax = cntA > cntB ? cntA : cntB;
    for (int j = 0; j < jmax; j += 4) {
      bool dA0 = j < cntA, dA1 = j + 2 < cntA;
      bool dB0 = j < cntB, dB1 = j + 2 < cntB;
      float wA0, wA1, wB0, wB1;
      us8 fA0, fA1, fB0, fB1;
      if (dA0) {
        int jj = j + half; bool v = jj < cntA; int jc = v ? jj : j;
        int s = sls[wave][0][jc];
        wA0 = v ? wls[wave][0][jc * 8 + h2] : 0.f;
        fA0 = *(const us8*)((const char*)feat + (((unsigned)s << 9) + idx16));
      }
      if (dA1) {
        int jj = j + 2 + half; bool v = jj < cntA; int jc = v ? jj : j + 2;
        int s = sls[wave][0][jc];
        wA1 = v ? wls[wave][0][jc * 8 + h2] : 0.f;
        fA1 = *(const us8*)((const char*)feat + (((unsigned)s << 9) + idx16));
      }
      if (dB0) {
        int jj = j + half; bool v = jj < cntB; int jc = v ? jj : j;
        int s = sls[wave][1][jc];
        wB0 = v ? wls[wave][1][jc * 8 + h2] : 0.f;
        fB0 = *(const us8*)((const char*)feat + (((unsigned)s << 9) + idx16));
      }
      if (dB1) {
        int jj = j + 2 + half; bool v = jj < cntB; int jc = v ? jj : j + 2;
        int s = sls[wave][1][jc];
        wB1 = v ? wls[wave][1][jc * 8 + h2] : 0.f;
        fB1 = *(const us8*)((const char*)feat + (((unsigned)s << 9) + idx16));
      }
      if (dA0) {
        aA0 += wA0 * b2f(fA0[0]); aA1 += wA0 * b2f(fA0[1]);
        aA2 += wA0 * b2f(fA0[2]); aA3 += wA0 * b2f(fA0[3]);
        aA4 += wA0 * b2f(fA0[4]); aA5 += wA0 * b2f(fA0[5]);
        aA6 += wA0 * b2f(fA0[6]); aA7 += wA0 * b2f(fA0[7]);
      }
      if (dA1) {
        aA0 += wA1 * b2f(fA1[0]); aA1 += wA1 * b2f(fA1[1]);
        aA2 += wA1 * b2f(fA1[2]); aA3 += wA1 * b2f(fA1[3]);
        aA4 += wA1 * b2f(fA1[4]); aA5 += wA1 * b2f(fA1[5]);
        aA6 += wA1 * b2f(fA1[6]); aA7 += wA1 * b2f(fA1[7]);
      }
      if (dB0) {
        aB0 += wB0 * b2f(fB0[0]); aB1 += wB0 * b2f(fB0[1]);
        aB2 += wB0 * b2f(fB0[2]); aB3 += wB0 * b2f(fB0[3]);
        aB4 += wB0 * b2f(fB0[4]); aB5 += wB0 * b2f(fB0[5]);
        aB6 += wB0 * b2f(fB0[6]); aB7 += wB0 * b2f(fB0[7]);
      }
      if (dB1) {
        aB0 += wB1 * b2f(fB1[0]); aB1 += wB1 * b2f(fB1[1]);
        aB2 += wB1 * b2f(fB1[2]); aB3 += wB1 * b2f(fB1[3]);
        aB4 += wB1 * b2f(fB1[4]); aB5 += wB1 * b2f(fB1[5]);
        aB6 += wB1 * b2f(fB1[6]); aB7 += wB1 * b2f(fB1[7]);
      }
    }
    cbA += 32; cbB += 32;
  }
  // combine halves (alternating-edge partials)
  aA0 += __shfl_xor(aA0, 32); aA1 += __shfl_xor(aA1, 32);
  aA2 += __shfl_xor(aA2, 32); aA3 += __shfl_xor(aA3, 32);
  aA4 += __shfl_xor(aA4, 32); aA5 += __shfl_xor(aA5, 32);
  aA6 += __shfl_xor(aA6, 32); aA7 += __shfl_xor(aA7, 32);
  aB0 += __shfl_xor(aB0, 32); aB1 += __shfl_xor(aB1, 32);
  aB2 += __shfl_xor(aB2, 32); aB3 += __shfl_xor(aB3, 32);
  aB4 += __shfl_xor(aB4, 32); aB5 += __shfl_xor(aB5, 32);
  aB6 += __shfl_xor(aB6, 32); aB7 += __shfl_xor(aB7, 32);
  // denom: reduce over edge-slot bits; lane i holds head i&7 total
  dsumA += __shfl_xor(dsumA, 8);
  dsumA += __shfl_xor(dsumA, 16);
  dsumA += __shfl_xor(dsumA, 32);
  dsumB += __shfl_xor(dsumB, 8);
  dsumB += __shfl_xor(dsumB, 16);
  dsumB += __shfl_xor(dsumB, 32);
  float dhA = __shfl(dsumA, h2);
  float dhB = __shfl(dsumB, h2);
  float invA = __builtin_amdgcn_rcpf(dhA > 0.f ? dhA : 1.f);
  float invB = __builtin_amdgcn_rcpf(dhB > 0.f ? dhB : 1.f);
  f32x4 blo = *(const f32x4*)(bias + l5 * 8);
  f32x4 bhi = *(const f32x4*)(bias + l5 * 8 + 4);
  float rA0 = aA0 * invA + blo.x, rA1 = aA1 * invA + blo.y;
  float rA2 = aA2 * invA + blo.z, rA3 = aA3 * invA + blo.w;
  float rA4 = aA4 * invA + bhi.x, rA5 = aA5 * invA + bhi.y;
  float rA6 = aA6 * invA + bhi.z, rA7 = aA7 * invA + bhi.w;
  float rB0 = aB0 * invB + blo.x, rB1 = aB1 * invB + blo.y;
  float rB2 = aB2 * invB + blo.z, rB3 = aB3 * invB + blo.w;
  float rB4 = aB4 * invB + bhi.x, rB5 = aB5 * invB + bhi.y;
  float rB6 = aB6 * invB + bhi.z, rB7 = aB7 * invB + bhi.w;
  rA0 = rA0 > 0.f ? rA0 : __expf(rA0) - 1.f;   // ELU (no libm)
  rA1 = rA1 > 0.f ? rA1 : __expf(rA1) - 1.f;
  rA2 = rA2 > 0.f ? rA2 : __expf(rA2) - 1.f;
  rA3 = rA3 > 0.f ? rA3 : __expf(rA3) - 1.f;
  rA4 = rA4 > 0.f ? rA4 : __expf(rA4) - 1.f;
  rA5 = rA5 > 0.f ? rA5 : __expf(rA5) - 1.f;
  rA6 = rA6 > 0.f ? rA6 : __expf(rA6) - 1.f;
  rA7 = rA7 > 0.f ? rA7 : __expf(rA7) - 1.f;
  rB0 = rB0 > 0.f ? rB0 : __expf(rB0) - 1.f;
  rB1 = rB1 > 0.f ? rB1 : __expf(rB1) - 1.f;
  rB2 = rB2 > 0.f ? rB2 : __expf(rB2) - 1.f;
  rB3 = rB3 > 0.f ? rB3 : __expf(rB3) - 1.f;
  rB4 = rB4 > 0.f ? rB4 : __expf(rB4) - 1.f;
  rB5 = rB5 > 0.f ? rB5 : __expf(rB5) - 1.f;
  rB6 = rB6 > 0.f ? rB6 : __expf(rB6) - 1.f;
  rB7 = rB7 > 0.f ? rB7 : __expf(rB7) - 1.f;
  f32x4 loA = {rA0, rA1, rA2, rA3};
  f32x4 hiA = {rA4, rA5, rA6, rA7};
  f32x4 loB = {rB0, rB1, rB2, rB3};
  f32x4 hiB = {rB4, rB5, rB6, rB7};
  f32x4 ovA = half ? hiA : loA;
  f32x4 ovB = half ? hiB : loB;
  if (y == 0) {
    *(f32x4*)((char*)za + (size_t)nA * 1024 + l5 * 32 + half * 16) = ovA;
    *(f32x4*)((char*)za + (size_t)nB * 1024 + l5 * 32 + half * 16) = ovB;
  } else {
    us4 oA, oB;
    oA.x = f2b(ovA.x); oA.y = f2b(ovA.y); oA.z = f2b(ovA.z); oA.w = f2b(ovA.w);
    oB.x = f2b(ovB.x); oB.y = f2b(ovB.y); oB.z = f2b(ovB.z); oB.w = f2b(ovB.w);
    *(us4*)((char*)zb + (size_t)nA * 512 + l5 * 16 + half * 8) = oA;
    *(us4*)((char*)zb + (size_t)nB * 512 + l5 * 16 + half * 8) = oB;
  }
}

// ---------------- semantic scores via MFMA ---------------------------------
__global__ __launch_bounds__(256)
void k_sem(const float* __restrict__ za,
           const unsigned short* __restrict__ zb,
           const unsigned short* __restrict__ w1t,
           const float* __restrict__ b1,
           const float* __restrict__ W2,
           float* __restrict__ wacc) {
  __shared__ us8 w1l[4096];                     // 128 rows x 32 chunks, 64KB
  int t = threadIdx.x;
  for (int i = t; i < 4096; i += 256) {
    int j = i >> 5, c = i & 31;
    w1l[j * 32 + (c ^ (j & 7))] = ((const us8*)w1t)[i];
  }
  __syncthreads();
  int lane = t & 63, wave = t >> 6;
  int col = lane & 15, quad = lane >> 4;
  float b1v[8], w2v[8];
#pragma unroll
  for (int tt = 0; tt < 8; ++tt) {
    b1v[tt] = b1[tt * 16 + col];
    w2v[tt] = W2[tt * 16 + col];
  }
  int gw = blockIdx.x * 4 + wave;
  int nw = gridDim.x * 4;
  float sa = 0.f, sb = 0.f;
  for (int gt = gw; gt < 6250; gt += nw) {
    f32x4 acc[8];
#pragma unroll
    for (int tt = 0; tt < 8; ++tt) acc[tt] = (f32x4){0.f, 0.f, 0.f, 0.f};
#pragma unroll
    for (int ks = 0; ks < 8; ++ks) {
      bf16x8 a;
      if (gt < 3125) {
        const float* ap = za + (size_t)gt * 4096 + col * 256 + ks * 32 + quad * 8;
        f32x4 a0 = *(const f32x4*)ap;
        f32x4 a1 = *(const f32x4*)(ap + 4);
        a[0] = (short)f2b(a0.x); a[1] = (short)f2b(a0.y);
        a[2] = (short)f2b(a0.z); a[3] = (short)f2b(a0.w);
        a[4] = (short)f2b(a1.x); a[5] = (short)f2b(a1.y);
        a[6] = (short)f2b(a1.z); a[7] = (short)f2b(a1.w);
      } else {
        a = *(const bf16x8*)(zb + (size_t)(gt - 3125) * 4096 + col * 256 +
                             ks * 32 + quad * 8);
      }
      int c = ks * 4 + quad;
#pragma unroll
      for (int tt = 0; tt < 8; ++tt) {
        int j = tt * 16 + col;
        bf16x8 b = (bf16x8)w1l[j * 32 + (c ^ (j & 7))];
        acc[tt] = __builtin_amdgcn_mfma_f32_16x16x32_bf16(a, b, acc[tt], 0, 0, 0);
      }
    }
    float tot = 0.f;
#pragma unroll
    for (int tt = 0; tt < 8; ++tt)
#pragma unroll
      for (int r = 0; r < 4; ++r) {
        float x = acc[tt][r] + b1v[tt];
        x = fminf(fmaxf(x, -10.f), 10.f);       // clamp for exp overflow
        float ex = __expf(2.f * x);             // tanh = (e^2x-1)/(e^2x+1)
        tot += (ex - 1.f) * __builtin_amdgcn_rcpf(ex + 1.f) * w2v[tt];
      }
#pragma unroll
    for (int off = 1; off < 64; off <<= 1) tot += __shfl_xor(tot, off);
    if (gt < 3125) sa += tot; else sb += tot;
  }
  if (lane == 0) {
    if (sa != 0.f) atomicAdd(&wacc[0], sa);
    if (sb != 0.f) atomicAdd(&wacc[1], sb);
  }
}

// ---------------- beta softmax + combine (in-place over za==out) -----------
__global__ __launch_bounds__(256)
void k_combine(const float* __restrict__ za,
               const unsigned short* __restrict__ zb,
               const float* __restrict__ wacc,
               float* __restrict__ out) {
  int i = blockIdx.x * 256 + threadIdx.x;       // 3.2M groups of 4
  float wa = wacc[0] * (1.f / kN), wb = wacc[1] * (1.f / kN);
  float mx = fmaxf(wa, wb);
  float ea = __expf(wa - mx), eb = __expf(wb - mx);
  float inv = __builtin_amdgcn_rcpf(ea + eb);
  float ba = ea * inv, bb = eb * inv;
  f32x4 x = ((const f32x4*)za)[i];
  us4 yv = ((const us4*)zb)[i];
  f32x4 o;
#pragma unroll
  for (int j = 0; j < 4; ++j)
    o[j] = ba * x[j] + bb * b2f(yv[j]);
  ((f32x4*)out)[i] = o;
}

extern "C" void kernel_launch(void* const* d_in, const int* in_sizes, int n_in,
                              void* d_out, int out_size, void* d_ws, size_t ws_size,
                              hipStream_t stream) {
  const float* hin = (const float*)d_in[0];
  const int* src_a = (const int*)d_in[1];
  const int* dst_a = (const int*)d_in[2];
  const int* src_b = (const int*)d_in[3];
  const int* dst_b = (const int*)d_in[4];
  const float* W_a = (const float*)d_in[5];
  const float* al_a = (const float*)d_in[6];
  const float* ar_a = (const float*)d_in[7];
  const float* bias_a = (const float*)d_in[8];
  const float* W_b = (const float*)d_in[9];
  const float* al_b = (const float*)d_in[10];
  const float* ar_b = (const float*)d_in[11];
  const float* bias_b = (const float*)d_in[12];
  const float* sW1 = (const float*)d_in[13];
  const float* sb1 = (const float*)d_in[14];
  const float* sW2 = (const float*)d_in[15];
  float* out = (float*)d_out;

  char* wsb = (char*)d_ws;
  size_t off = 0;
  auto alloc = [&](size_t bytes) -> char* {
    char* p = wsb + off;
    off = (off + bytes + 511) & ~(size_t)511;
    return p;
  };
  // Footprint ~98 MB.
  unsigned short* feat_a = (unsigned short*)alloc((size_t)kN * 256 * 2); // 25.6MB
  unsigned short* feat_b = (unsigned short*)alloc((size_t)kN * 256 * 2); // 25.6MB
  unsigned short* z_b    = (unsigned short*)alloc((size_t)kN * 256 * 2); // 25.6MB
  float* el_a = (float*)alloc((size_t)kN * 8 * 4);
  float* er_a = (float*)alloc((size_t)kN * 8 * 4);
  float* el_b = (float*)alloc((size_t)kN * 8 * 4);
  float* er_b = (float*)alloc((size_t)kN * 8 * 4);
  unsigned short* wt_a = (unsigned short*)alloc(65536 * 2);
  unsigned short* wt_b = (unsigned short*)alloc(65536 * 2);
  unsigned short* w1t  = (unsigned short*)alloc(32768 * 2);
  int* rp_a = (int*)alloc((size_t)(kN + 1) * 4);
  int* rp_b = (int*)alloc((size_t)(kN + 1) * 4);
  int* es_a = (int*)alloc((size_t)kE * 4);
  int* es_b = (int*)alloc((size_t)kE * 4);
  unsigned* pay = (unsigned*)alloc((size_t)2 * kNBUK * kCAP * 4);  // 7.2MB
  int* cnt = (int*)alloc((size_t)2 * kNBUK * 4);
  int* bbase = (int*)alloc((size_t)2 * kNBUK * 4);
  float* wacc = (float*)alloc(2 * 4);

  hipMemsetAsync(cnt, 0, (size_t)2 * kNBUK * 4, stream);
  hipMemsetAsync(wacc, 0, 8, stream);

  k_prep<<<640, 256, 0, stream>>>(W_a, W_b, sW1, wt_a, wt_b, w1t);
  k_part<<<dim3(125, 2), 256, 0, stream>>>(src_a, dst_a, src_b, dst_b, cnt, pay);
  k_bscan<<<1, 256, 0, stream>>>(cnt, bbase, rp_a, rp_b);
  k_bucket<<<dim3(kNBUK, 2), 256, 0, stream>>>(cnt, bbase, pay,
                                               rp_a, rp_b, es_a, es_b);
  k_gemm<<<dim3(391, 2), 512, 0, stream>>>(hin, wt_a, wt_b,
                                           al_a, ar_a, al_b, ar_b,
                                           feat_a, feat_b,
                                           el_a, er_a, el_b, er_b);
  k_agg<<<12500, 256, 0, stream>>>(rp_a, rp_b, es_a, es_b,
                                   el_a, er_a, el_b, er_b,
                                   feat_a, feat_b, bias_a, bias_b,
                                   out, z_b);
  k_sem<<<512, 256, 0, stream>>>(out, z_b, w1t, sb1, sW2, wacc);
  k_combine<<<12500, 256, 0, stream>>>(out, z_b, wacc, out);
}